// Round 12
// baseline (108.618 us; speedup 1.0000x reference)
//
#include <hip/hip_runtime.h>

#define TEMP 5.656854249492380195f   // sqrt(32)
#define EPSG 1e-10f

// K1 GEMM geometry: M-tile 64 (8 b x 8 v), N 64 (q|k), K chunk 64, 8 chunks.
#define XSTR 68                      // x-tile row stride (floats)
#define WSTR 64                      // w-tile row stride

// ---------- K1: proj GEMM (reg-prefetch dbuf) + argmax + hmean(LDS)
// ----------     + merged q2 GEMM + rule argmax + bucket append ------------
__launch_bounds__(256, 2)
__global__ void k1_kernel(const float* __restrict__ hidden,
                          const float* __restrict__ u_var,
                          const float* __restrict__ u_rule,
                          const float* __restrict__ Wq,
                          const float* __restrict__ bq,
                          const float* __restrict__ Wk,
                          const float* __restrict__ bk,
                          const float* __restrict__ rule_emb,
                          const float* __restrict__ Wk2,
                          const float* __restrict__ bk2,
                          const float* __restrict__ Wq2,
                          const float* __restrict__ bq2,
                          int* __restrict__ cnt,
                          int* __restrict__ selbuf,
                          int* __restrict__ list) {
    const int tid = threadIdx.x;
    const int b0  = blockIdx.x * 8;

    __shared__ float  xt[64 * XSTR];     // 17.4 KB; epilogue scores alias here
    __shared__ float  wt[64 * WSTR];     // 16 KB
    __shared__ float  hm[8 * 512];       // 16 KB hmean
    __shared__ float  sk2[512];          // k2 = rule_emb@Wk2+bk2
    __shared__ float  xt2[8][256];       // q2-phase x tile
    __shared__ float4 part4[4][8][8];
    __shared__ float  sq2[8][32];
    __shared__ int    ssel[8];

    const int tn = tid & 15;
    const int tm = tid >> 4;

    float4 acc0 = make_float4(0.f, 0.f, 0.f, 0.f);
    float4 acc1 = make_float4(0.f, 0.f, 0.f, 0.f);
    float4 acc2 = make_float4(0.f, 0.f, 0.f, 0.f);
    float4 acc3 = make_float4(0.f, 0.f, 0.f, 0.f);

    // staging address components (fixed per thread)
    const int xrow = tid >> 4;            // reuse per p via f = p*256+tid
    float4 px[4], pw[4];

    // ---- prologue: load chunk 0 ----
    #pragma unroll
    for (int p = 0; p < 4; ++p) {
        int f = p * 256 + tid;
        int row = f >> 4, c4 = f & 15;
        int bb = row >> 3, v = row & 7;
        px[p] = *reinterpret_cast<const float4*>(
            hidden + (size_t)(b0 + bb) * 4096 + v * 512 + 0 * 64 + c4 * 4);
        int k = row, n4 = c4;
        const float* src = (n4 < 8) ? (Wq + (0 * 64 + k) * 32 + n4 * 4)
                                    : (Wk + (0 * 64 + k) * 32 + (n4 - 8) * 4);
        pw[p] = *reinterpret_cast<const float4*>(src);
    }
    #pragma unroll
    for (int p = 0; p < 4; ++p) {
        int f = p * 256 + tid;
        int row = f >> 4, c4 = f & 15;
        *reinterpret_cast<float4*>(&xt[row * XSTR + c4 * 4]) = px[p];
        *reinterpret_cast<float4*>(&wt[row * WSTR + c4 * 4]) = pw[p];
    }
    __syncthreads();

    for (int c = 0; c < 8; ++c) {
        // ---- issue prefetch for chunk c+1 (lands during compute) ----
        if (c < 7) {
            #pragma unroll
            for (int p = 0; p < 4; ++p) {
                int f = p * 256 + tid;
                int row = f >> 4, c4 = f & 15;
                int bb = row >> 3, v = row & 7;
                px[p] = *reinterpret_cast<const float4*>(
                    hidden + (size_t)(b0 + bb) * 4096 + v * 512 + (c + 1) * 64 + c4 * 4);
                const float* src = (c4 < 8) ? (Wq + ((c + 1) * 64 + row) * 32 + c4 * 4)
                                            : (Wk + ((c + 1) * 64 + row) * 32 + (c4 - 8) * 4);
                pw[p] = *reinterpret_cast<const float4*>(src);
            }
        }

        // ---- compute: 16 k4-steps, 8 ds_read_b128 : 64 FMA each ----
        #pragma unroll 4
        for (int k4 = 0; k4 < 16; ++k4) {
            float4 x0 = *reinterpret_cast<const float4*>(&xt[(tm * 4 + 0) * XSTR + k4 * 4]);
            float4 x1 = *reinterpret_cast<const float4*>(&xt[(tm * 4 + 1) * XSTR + k4 * 4]);
            float4 x2 = *reinterpret_cast<const float4*>(&xt[(tm * 4 + 2) * XSTR + k4 * 4]);
            float4 x3 = *reinterpret_cast<const float4*>(&xt[(tm * 4 + 3) * XSTR + k4 * 4]);
            float4 w0 = *reinterpret_cast<const float4*>(&wt[(k4 * 4 + 0) * WSTR + tn * 4]);
            float4 w1 = *reinterpret_cast<const float4*>(&wt[(k4 * 4 + 1) * WSTR + tn * 4]);
            float4 w2 = *reinterpret_cast<const float4*>(&wt[(k4 * 4 + 2) * WSTR + tn * 4]);
            float4 w3 = *reinterpret_cast<const float4*>(&wt[(k4 * 4 + 3) * WSTR + tn * 4]);
            acc0.x += x0.x * w0.x + x0.y * w1.x + x0.z * w2.x + x0.w * w3.x;
            acc0.y += x0.x * w0.y + x0.y * w1.y + x0.z * w2.y + x0.w * w3.y;
            acc0.z += x0.x * w0.z + x0.y * w1.z + x0.z * w2.z + x0.w * w3.z;
            acc0.w += x0.x * w0.w + x0.y * w1.w + x0.z * w2.w + x0.w * w3.w;
            acc1.x += x1.x * w0.x + x1.y * w1.x + x1.z * w2.x + x1.w * w3.x;
            acc1.y += x1.x * w0.y + x1.y * w1.y + x1.z * w2.y + x1.w * w3.y;
            acc1.z += x1.x * w0.z + x1.y * w1.z + x1.z * w2.z + x1.w * w3.z;
            acc1.w += x1.x * w0.w + x1.y * w1.w + x1.z * w2.w + x1.w * w3.w;
            acc2.x += x2.x * w0.x + x2.y * w1.x + x2.z * w2.x + x2.w * w3.x;
            acc2.y += x2.x * w0.y + x2.y * w1.y + x2.z * w2.y + x2.w * w3.y;
            acc2.z += x2.x * w0.z + x2.y * w1.z + x2.z * w2.z + x2.w * w3.z;
            acc2.w += x2.x * w0.w + x2.y * w1.w + x2.z * w2.w + x2.w * w3.w;
            acc3.x += x3.x * w0.x + x3.y * w1.x + x3.z * w2.x + x3.w * w3.x;
            acc3.y += x3.x * w0.y + x3.y * w1.y + x3.z * w2.y + x3.w * w3.y;
            acc3.z += x3.x * w0.z + x3.y * w1.z + x3.z * w2.z + x3.w * w3.z;
            acc3.w += x3.x * w0.w + x3.y * w1.w + x3.z * w2.w + x3.w * w3.w;
        }

        // ---- hmean partial for this chunk (reads xt; v ascending) ----
        {
            int bb = tid >> 5, hg = tid & 31;
            float m0 = 0.f, m1 = 0.f;
            #pragma unroll
            for (int v = 0; v < 8; ++v) {
                float2 x2 = *reinterpret_cast<const float2*>(&xt[(bb * 8 + v) * XSTR + hg * 2]);
                m0 += x2.x; m1 += x2.y;
            }
            hm[bb * 512 + c * 64 + hg * 2]     = m0 * 0.125f;
            hm[bb * 512 + c * 64 + hg * 2 + 1] = m1 * 0.125f;
        }
        __syncthreads();

        // ---- write prefetched chunk ----
        if (c < 7) {
            #pragma unroll
            for (int p = 0; p < 4; ++p) {
                int f = p * 256 + tid;
                int row = f >> 4, c4 = f & 15;
                *reinterpret_cast<float4*>(&xt[row * XSTR + c4 * 4]) = px[p];
                *reinterpret_cast<float4*>(&wt[row * WSTR + c4 * 4]) = pw[p];
            }
            __syncthreads();
        }
    }

    // ---- epilogue: bias + write scores to LDS (aliases xt region) ----
    {
        const float* bsrc = (tn < 8) ? (bq + tn * 4) : (bk + (tn - 8) * 4);
        float4 bias4 = *reinterpret_cast<const float4*>(bsrc);
        float4 r0, r1, r2, r3;
        r0.x = acc0.x + bias4.x; r0.y = acc0.y + bias4.y; r0.z = acc0.z + bias4.z; r0.w = acc0.w + bias4.w;
        r1.x = acc1.x + bias4.x; r1.y = acc1.y + bias4.y; r1.z = acc1.z + bias4.z; r1.w = acc1.w + bias4.w;
        r2.x = acc2.x + bias4.x; r2.y = acc2.y + bias4.y; r2.z = acc2.z + bias4.z; r2.w = acc2.w + bias4.w;
        r3.x = acc3.x + bias4.x; r3.y = acc3.y + bias4.y; r3.z = acc3.z + bias4.z; r3.w = acc3.w + bias4.w;
        *reinterpret_cast<float4*>(&xt[(tm * 4 + 0) * XSTR + tn * 4]) = r0;
        *reinterpret_cast<float4*>(&xt[(tm * 4 + 1) * XSTR + tn * 4]) = r1;
        *reinterpret_cast<float4*>(&xt[(tm * 4 + 2) * XSTR + tn * 4]) = r2;
        *reinterpret_cast<float4*>(&xt[(tm * 4 + 3) * XSTR + tn * 4]) = r3;
    }
    __syncthreads();

    // ---- per-wave 64-lane argmax; wave w handles b0+w and b0+w+4 ----
    {
        const int w    = tid >> 6;
        const int lane = tid & 63;
        #pragma unroll
        for (int half = 0; half < 2; ++half) {
            const int bb = w + half * 4;
            const int b  = b0 + bb;
            const int i = lane >> 3, j = lane & 7;
            float s = 0.f;
            #pragma unroll
            for (int d4 = 0; d4 < 8; ++d4) {
                float4 qv = *reinterpret_cast<const float4*>(&xt[(bb * 8 + i) * XSTR + d4 * 4]);
                float4 kv = *reinterpret_cast<const float4*>(&xt[(bb * 8 + j) * XSTR + 32 + d4 * 4]);
                s += qv.x * kv.x + qv.y * kv.y + qv.z * kv.z + qv.w * kv.w;
            }
            s /= TEMP;
            float u = u_var[(size_t)b * 64 + lane];
            float g = -logf(-logf(u + EPSG) + EPSG);
            float pm = s + g;
            int idx = lane;
            #pragma unroll
            for (int off = 32; off >= 1; off >>= 1) {
                float pv = __shfl_xor(pm, off);
                int   pi = __shfl_xor(idx, off);
                if (pv > pm || (pv == pm && pi < idx)) { pm = pv; idx = pi; }
            }
            if (lane == 0) { selbuf[b] = idx; ssel[bb] = idx; }
        }
    }

    // ---- k2 = rule_emb@Wk2 + bk2 (per block; identical formula) ----
    for (int t = tid; t < 512; t += 256) {
        int r = t >> 5, d = t & 31;
        float acc = bk2[d];
        for (int h = 0; h < 64; ++h)
            acc += rule_emb[r * 64 + h] * Wk2[h * 32 + d];
        sk2[t] = acc;
    }
    __syncthreads();

    // ---- q2 GEMM (k2sel structure, FP order preserved) ----
    {
        const int d4 = tid & 7, s = tid >> 3;
        float4 acc[8];
        #pragma unroll
        for (int bb = 0; bb < 8; ++bb) acc[bb] = make_float4(0.f, 0.f, 0.f, 0.f);

        for (int kt = 0; kt < 4; ++kt) {
            float4 w[8];
            #pragma unroll
            for (int j = 0; j < 8; ++j)
                w[j] = *reinterpret_cast<const float4*>(Wq2 + (size_t)(kt * 256 + s * 8 + j) * 32 + d4 * 4);
            #pragma unroll
            for (int bb = 0; bb < 8; ++bb) {
                const int b  = b0 + bb;
                const int sv = ssel[bb];
                const float* src;
                if (kt < 2) src = hidden + ((size_t)b * 8 + (sv & 7))  * 512 + kt * 256;
                else        src = hidden + ((size_t)b * 8 + (sv >> 3)) * 512 + (kt - 2) * 256;
                xt2[bb][tid] = src[tid];
            }
            __syncthreads();
            #pragma unroll
            for (int bb = 0; bb < 8; ++bb) {
                #pragma unroll
                for (int j = 0; j < 8; ++j) {
                    float x = xt2[bb][s * 8 + j];
                    acc[bb].x += x * w[j].x;
                    acc[bb].y += x * w[j].y;
                    acc[bb].z += x * w[j].z;
                    acc[bb].w += x * w[j].w;
                }
            }
            __syncthreads();
        }
        for (int kt = 4; kt < 6; ++kt) {
            float4 w[8];
            #pragma unroll
            for (int j = 0; j < 8; ++j)
                w[j] = *reinterpret_cast<const float4*>(Wq2 + (size_t)(kt * 256 + s * 8 + j) * 32 + d4 * 4);
            #pragma unroll
            for (int bb = 0; bb < 8; ++bb) {
                #pragma unroll
                for (int j = 0; j < 8; ++j) {
                    float x = hm[bb * 512 + (kt - 4) * 256 + s * 8 + j];
                    acc[bb].x += x * w[j].x;
                    acc[bb].y += x * w[j].y;
                    acc[bb].z += x * w[j].z;
                    acc[bb].w += x * w[j].w;
                }
            }
        }
        #pragma unroll
        for (int off = 8; off < 64; off <<= 1) {
            #pragma unroll
            for (int bb = 0; bb < 8; ++bb) {
                acc[bb].x += __shfl_xor(acc[bb].x, off);
                acc[bb].y += __shfl_xor(acc[bb].y, off);
                acc[bb].z += __shfl_xor(acc[bb].z, off);
                acc[bb].w += __shfl_xor(acc[bb].w, off);
            }
        }
        if ((s & 7) == 0) {
            #pragma unroll
            for (int bb = 0; bb < 8; ++bb) part4[tid >> 6][bb][d4] = acc[bb];
        }
    }
    __syncthreads();
    {
        const int bb = tid >> 5, col = tid & 31;
        float q2 = bq2[col];
        #pragma unroll
        for (int wv = 0; wv < 4; ++wv) {
            const float* pf = reinterpret_cast<const float*>(&part4[wv][bb][col >> 2]);
            q2 += pf[col & 3];
        }
        sq2[bb][col] = q2;
    }
    __syncthreads();
    if (tid < 128) {
        const int bb = tid >> 4, r = tid & 15;
        const int b = b0 + bb;
        float sc = 0.f;
        #pragma unroll
        for (int d = 0; d < 32; ++d) sc += sq2[bb][d] * sk2[r * 32 + d];
        sc /= TEMP;
        float u = u_rule[(size_t)b * 16 + r];
        float g = -logf(-logf(u + EPSG) + EPSG);
        float pm = sc + g;
        int idx = r;
        #pragma unroll
        for (int off = 8; off >= 1; off >>= 1) {
            float pv = __shfl_xor(pm, off, 16);
            int   pi = __shfl_xor(idx, off, 16);
            if (pv > pm || (pv == pm && pi < idx)) { pm = pv; idx = pi; }
        }
        if (r == 0) {
            int pos = atomicAdd(&cnt[idx], 1);
            list[idx * 4096 + pos] = b;
        }
    }
}

// ---------- K3: rule-bucketed MLP + full output write ----------------------
__launch_bounds__(256, 2)
__global__ void k3_kernel(const float* __restrict__ hidden,
                          const float* __restrict__ W1,
                          const float* __restrict__ W2,
                          const int* __restrict__ selbuf,
                          const int* __restrict__ cnt,
                          const int* __restrict__ list,
                          float* __restrict__ outbuf) {
    const int tid = threadIdx.x;
    const int r   = blockIdx.x & 15;       // rule
    const int c   = blockIdx.x >> 4;       // chunk 0..31

    __shared__ float w1s[16384];           // W1[r] as [row*16+e] (64 KB)
    __shared__ float comb[1024];
    __shared__ float part[4][16];
    __shared__ float s_h1[16];

    #pragma unroll
    for (int i = 0; i < 16; ++i) {
        int idx = i * 1024 + tid * 4;
        *reinterpret_cast<float4*>(&w1s[idx]) =
            *reinterpret_cast<const float4*>(W1 + (size_t)r * 16384 + idx);
    }
    const int n = cnt[r];
    __syncthreads();

    const int e  = tid & 15;
    const int sl = tid >> 4;

    for (int idx = c; idx < n; idx += 32) {
        const int b  = list[r * 4096 + idx];
        const int sv = selbuf[b];
        const int js = sv & 7, cs = sv >> 3;

        {
            const float4* h4 = reinterpret_cast<const float4*>(hidden);
            float4 v;
            if (tid < 128) v = h4[((size_t)b * 8 + js) * 128 + tid];
            else           v = h4[((size_t)b * 8 + cs) * 128 + (tid - 128)];
            *reinterpret_cast<float4*>(&comb[tid * 4]) = v;
        }
        __syncthreads();

        float a = 0.f;
        for (int i = 0; i < 64; ++i) {
            int rr = i * 16 + sl;
            a += comb[rr] * w1s[rr * 16 + e];
        }
        a += __shfl_xor(a, 16);
        a += __shfl_xor(a, 32);
        if ((sl & 3) == 0) part[sl >> 2][e] = a;
        __syncthreads();
        if (tid < 16)
            s_h1[tid] = fmaxf(part[0][tid] + part[1][tid] + part[2][tid] + part[3][tid], 0.f);
        __syncthreads();

        const float* w2 = W2 + (size_t)r * 8192;
        int o0 = tid * 2;
        float a0 = 0.f, a1 = 0.f;
        #pragma unroll
        for (int ee = 0; ee < 16; ++ee) {
            float h1e = s_h1[ee];
            float2 ww = *reinterpret_cast<const float2*>(w2 + ee * 512 + o0);
            a0 += h1e * ww.x;
            a1 += h1e * ww.y;
        }
        float2 nz = make_float2(a0, a1);
        float2 zz = make_float2(0.f, 0.f);
        float2* ob = reinterpret_cast<float2*>(outbuf + (size_t)b * 4096);
        #pragma unroll
        for (int v = 0; v < 8; ++v)
            ob[v * 256 + tid] = (v == js) ? nz : zz;
    }
}

extern "C" void kernel_launch(void* const* d_in, const int* in_sizes, int n_in,
                              void* d_out, int out_size, void* d_ws, size_t ws_size,
                              hipStream_t stream) {
    const float* hidden   = (const float*)d_in[0];
    const float* u_var    = (const float*)d_in[1];
    const float* u_rule   = (const float*)d_in[2];
    const float* Wq       = (const float*)d_in[3];
    const float* bq       = (const float*)d_in[4];
    const float* Wk       = (const float*)d_in[5];
    const float* bk       = (const float*)d_in[6];
    const float* rule_emb = (const float*)d_in[7];
    const float* Wq2      = (const float*)d_in[8];
    const float* bq2      = (const float*)d_in[9];
    const float* Wk2      = (const float*)d_in[10];
    const float* bk2      = (const float*)d_in[11];
    const float* W1       = (const float*)d_in[12];
    const float* W2       = (const float*)d_in[13];

    char* ws = (char*)d_ws;
    int*   cnt  = (int*)(ws + 2048);         // 16 i32
    int*   sel  = (int*)(ws + 4096);         // 4096 i32
    int*   list = (int*)(ws + 20480);        // 16*4096 i32
    float* outf = (float*)d_out;

    hipMemsetAsync(cnt, 0, 64, stream);
    hipLaunchKernelGGL(k1_kernel, dim3(512), dim3(256), 0, stream,
                       hidden, u_var, u_rule, Wq, bq, Wk, bk,
                       rule_emb, Wk2, bk2, Wq2, bq2, cnt, sel, list);
    hipLaunchKernelGGL(k3_kernel, dim3(512), dim3(256), 0, stream,
                       hidden, W1, W2, sel, cnt, list, outf);
}

// Round 13
// 96.268 us; speedup vs baseline: 1.1283x; 1.1283x over previous
//
#include <hip/hip_runtime.h>

#define TEMP 5.656854249492380195f   // sqrt(32)
#define EPSG 1e-10f

// K1 GEMM geometry: M-tile 64 (8 b x 8 v), N 64 (q|k), K chunk 64, 8 chunks.
#define XSTR 68                      // x-tile row stride (floats)
#define WSTR 64                      // w-tile row stride

// ---------- K1: canonical LDS GEMM for q/k projection + argmax + hmean -----
// (reverted to the round-11 50us version; only the dead cnt-zeroing removed)
__launch_bounds__(256, 2)
__global__ void k1_kernel(const float* __restrict__ hidden,
                          const float* __restrict__ u_var,
                          const float* __restrict__ Wq,
                          const float* __restrict__ bq,
                          const float* __restrict__ Wk,
                          const float* __restrict__ bk,
                          const float* __restrict__ rule_emb,
                          const float* __restrict__ Wk2,
                          const float* __restrict__ bk2,
                          float* __restrict__ k2f,
                          int* __restrict__ selbuf,
                          float* __restrict__ outbuf) {
    const int tid = threadIdx.x;
    const int b0  = blockIdx.x * 8;

    __shared__ float4 smem4[(64 * XSTR + 64 * WSTR) / 4];
    float* smem = reinterpret_cast<float*>(smem4);
    float* xt = smem;
    float* wt = smem + 64 * XSTR;

    // merged K0 (block 0 only): k2 = rule_emb@Wk2 + bk2
    if (blockIdx.x == 0) {
        for (int t = tid; t < 512; t += 256) {
            int r = t >> 5, d = t & 31;
            float acc = bk2[d];
            for (int h = 0; h < 64; ++h)
                acc += rule_emb[r * 64 + h] * Wk2[h * 32 + d];
            k2f[t] = acc;
        }
    }

    const int tn = tid & 15;
    const int tm = tid >> 4;

    float4 acc0 = make_float4(0.f, 0.f, 0.f, 0.f);
    float4 acc1 = make_float4(0.f, 0.f, 0.f, 0.f);
    float4 acc2 = make_float4(0.f, 0.f, 0.f, 0.f);
    float4 acc3 = make_float4(0.f, 0.f, 0.f, 0.f);

    for (int c = 0; c < 8; ++c) {
        #pragma unroll
        for (int p = 0; p < 4; ++p) {
            int f   = p * 256 + tid;
            int row = f >> 4;
            int c4  = f & 15;
            int bb  = row >> 3, v = row & 7;
            float4 val = *reinterpret_cast<const float4*>(
                hidden + (size_t)(b0 + bb) * 4096 + v * 512 + c * 64 + c4 * 4);
            *reinterpret_cast<float4*>(&xt[row * XSTR + c4 * 4]) = val;
        }
        #pragma unroll
        for (int p = 0; p < 4; ++p) {
            int f  = p * 256 + tid;
            int k  = f >> 4;
            int n4 = f & 15;
            int h  = c * 64 + k;
            const float* src = (n4 < 8) ? (Wq + h * 32 + n4 * 4)
                                        : (Wk + h * 32 + (n4 - 8) * 4);
            *reinterpret_cast<float4*>(&wt[k * WSTR + n4 * 4]) =
                *reinterpret_cast<const float4*>(src);
        }
        __syncthreads();

        #pragma unroll 4
        for (int k4 = 0; k4 < 16; ++k4) {
            float4 x0 = *reinterpret_cast<const float4*>(&xt[(tm * 4 + 0) * XSTR + k4 * 4]);
            float4 x1 = *reinterpret_cast<const float4*>(&xt[(tm * 4 + 1) * XSTR + k4 * 4]);
            float4 x2 = *reinterpret_cast<const float4*>(&xt[(tm * 4 + 2) * XSTR + k4 * 4]);
            float4 x3 = *reinterpret_cast<const float4*>(&xt[(tm * 4 + 3) * XSTR + k4 * 4]);
            float4 w0 = *reinterpret_cast<const float4*>(&wt[(k4 * 4 + 0) * WSTR + tn * 4]);
            float4 w1 = *reinterpret_cast<const float4*>(&wt[(k4 * 4 + 1) * WSTR + tn * 4]);
            float4 w2 = *reinterpret_cast<const float4*>(&wt[(k4 * 4 + 2) * WSTR + tn * 4]);
            float4 w3 = *reinterpret_cast<const float4*>(&wt[(k4 * 4 + 3) * WSTR + tn * 4]);
            acc0.x += x0.x * w0.x + x0.y * w1.x + x0.z * w2.x + x0.w * w3.x;
            acc0.y += x0.x * w0.y + x0.y * w1.y + x0.z * w2.y + x0.w * w3.y;
            acc0.z += x0.x * w0.z + x0.y * w1.z + x0.z * w2.z + x0.w * w3.z;
            acc0.w += x0.x * w0.w + x0.y * w1.w + x0.z * w2.w + x0.w * w3.w;
            acc1.x += x1.x * w0.x + x1.y * w1.x + x1.z * w2.x + x1.w * w3.x;
            acc1.y += x1.x * w0.y + x1.y * w1.y + x1.z * w2.y + x1.w * w3.y;
            acc1.z += x1.x * w0.z + x1.y * w1.z + x1.z * w2.z + x1.w * w3.z;
            acc1.w += x1.x * w0.w + x1.y * w1.w + x1.z * w2.w + x1.w * w3.w;
            acc2.x += x2.x * w0.x + x2.y * w1.x + x2.z * w2.x + x2.w * w3.x;
            acc2.y += x2.x * w0.y + x2.y * w1.y + x2.z * w2.y + x2.w * w3.y;
            acc2.z += x2.x * w0.z + x2.y * w1.z + x2.z * w2.z + x2.w * w3.z;
            acc2.w += x2.x * w0.w + x2.y * w1.w + x2.z * w2.w + x2.w * w3.w;
            acc3.x += x3.x * w0.x + x3.y * w1.x + x3.z * w2.x + x3.w * w3.x;
            acc3.y += x3.x * w0.y + x3.y * w1.y + x3.z * w2.y + x3.w * w3.y;
            acc3.z += x3.x * w0.z + x3.y * w1.z + x3.z * w2.z + x3.w * w3.z;
            acc3.w += x3.x * w0.w + x3.y * w1.w + x3.z * w2.w + x3.w * w3.w;
        }

        {
            int bb = tid >> 5, hg = tid & 31;
            float m0 = 0.f, m1 = 0.f;
            #pragma unroll
            for (int v = 0; v < 8; ++v) {
                float2 x2 = *reinterpret_cast<const float2*>(&xt[(bb * 8 + v) * XSTR + hg * 2]);
                m0 += x2.x; m1 += x2.y;
            }
            float2 o; o.x = m0 * 0.125f; o.y = m1 * 0.125f;
            *reinterpret_cast<float2*>(outbuf + (size_t)(b0 + bb) * 4096 + c * 64 + hg * 2) = o;
        }
        __syncthreads();
    }

    {
        const float* bsrc = (tn < 8) ? (bq + tn * 4) : (bk + (tn - 8) * 4);
        float4 bias4 = *reinterpret_cast<const float4*>(bsrc);
        float4 r0, r1, r2, r3;
        r0.x = acc0.x + bias4.x; r0.y = acc0.y + bias4.y; r0.z = acc0.z + bias4.z; r0.w = acc0.w + bias4.w;
        r1.x = acc1.x + bias4.x; r1.y = acc1.y + bias4.y; r1.z = acc1.z + bias4.z; r1.w = acc1.w + bias4.w;
        r2.x = acc2.x + bias4.x; r2.y = acc2.y + bias4.y; r2.z = acc2.z + bias4.z; r2.w = acc2.w + bias4.w;
        r3.x = acc3.x + bias4.x; r3.y = acc3.y + bias4.y; r3.z = acc3.z + bias4.z; r3.w = acc3.w + bias4.w;
        float* sq = smem;
        *reinterpret_cast<float4*>(&sq[(tm * 4 + 0) * XSTR + tn * 4]) = r0;
        *reinterpret_cast<float4*>(&sq[(tm * 4 + 1) * XSTR + tn * 4]) = r1;
        *reinterpret_cast<float4*>(&sq[(tm * 4 + 2) * XSTR + tn * 4]) = r2;
        *reinterpret_cast<float4*>(&sq[(tm * 4 + 3) * XSTR + tn * 4]) = r3;
    }
    __syncthreads();

    {
        const float* sq = smem;
        const int w    = tid >> 6;
        const int lane = tid & 63;
        #pragma unroll
        for (int half = 0; half < 2; ++half) {
            const int bb = w + half * 4;
            const int b  = b0 + bb;
            const int i = lane >> 3, j = lane & 7;
            float s = 0.f;
            #pragma unroll
            for (int d4 = 0; d4 < 8; ++d4) {
                float4 qv = *reinterpret_cast<const float4*>(&sq[(bb * 8 + i) * XSTR + d4 * 4]);
                float4 kv = *reinterpret_cast<const float4*>(&sq[(bb * 8 + j) * XSTR + 32 + d4 * 4]);
                s += qv.x * kv.x + qv.y * kv.y + qv.z * kv.z + qv.w * kv.w;
            }
            s /= TEMP;
            float u = u_var[(size_t)b * 64 + lane];
            float g = -logf(-logf(u + EPSG) + EPSG);
            float pm = s + g;
            int idx = lane;
            #pragma unroll
            for (int off = 32; off >= 1; off >>= 1) {
                float pv = __shfl_xor(pm, off);
                int   pi = __shfl_xor(idx, off);
                if (pv > pm || (pv == pm && pi < idx)) { pm = pv; idx = pi; }
            }
            if (lane == 0) selbuf[b] = idx;
        }
    }
}

// ---------- K2: q2 GEMM + rule gumbel argmax -> rsel[b] --------------------
__launch_bounds__(256, 4)
__global__ void k2sel_kernel(const float* __restrict__ hidden,
                             const float* __restrict__ u_rule,
                             const float* __restrict__ Wq2,
                             const float* __restrict__ bq2,
                             const float* __restrict__ k2f,
                             const int* __restrict__ selbuf,
                             const float* __restrict__ hmeanbuf,
                             int* __restrict__ rselbuf) {
    const int tid = threadIdx.x;
    const int b0 = blockIdx.x * 8;

    __shared__ float  s_k2[512];
    __shared__ float  xt[8][256];
    __shared__ float4 part4[4][8][8];
    __shared__ float  s_q2[8][32];
    __shared__ int    s_sel8[8];

    s_k2[tid]       = k2f[tid];
    s_k2[tid + 256] = k2f[tid + 256];
    if (tid < 8) s_sel8[tid] = selbuf[b0 + tid];
    __syncthreads();

    const int d4 = tid & 7, s = tid >> 3;
    float4 acc[8];
    #pragma unroll
    for (int bb = 0; bb < 8; ++bb) acc[bb] = make_float4(0.f, 0.f, 0.f, 0.f);

    for (int kt = 0; kt < 6; ++kt) {
        float4 w[8];
        #pragma unroll
        for (int j = 0; j < 8; ++j)
            w[j] = *reinterpret_cast<const float4*>(Wq2 + (size_t)(kt * 256 + s * 8 + j) * 32 + d4 * 4);
        #pragma unroll
        for (int bb = 0; bb < 8; ++bb) {
            const int b  = b0 + bb;
            const int sv = s_sel8[bb];
            const float* src;
            if (kt < 2)      src = hidden  + ((size_t)b * 8 + (sv & 7))  * 512 + kt * 256;
            else if (kt < 4) src = hidden  + ((size_t)b * 8 + (sv >> 3)) * 512 + (kt - 2) * 256;
            else             src = hmeanbuf + (size_t)b * 4096 + (kt - 4) * 256;
            xt[bb][tid] = src[tid];
        }
        __syncthreads();
        #pragma unroll
        for (int bb = 0; bb < 8; ++bb) {
            #pragma unroll
            for (int j = 0; j < 8; ++j) {
                float x = xt[bb][s * 8 + j];
                acc[bb].x += x * w[j].x;
                acc[bb].y += x * w[j].y;
                acc[bb].z += x * w[j].z;
                acc[bb].w += x * w[j].w;
            }
        }
        __syncthreads();
    }
    #pragma unroll
    for (int off = 8; off < 64; off <<= 1) {
        #pragma unroll
        for (int bb = 0; bb < 8; ++bb) {
            acc[bb].x += __shfl_xor(acc[bb].x, off);
            acc[bb].y += __shfl_xor(acc[bb].y, off);
            acc[bb].z += __shfl_xor(acc[bb].z, off);
            acc[bb].w += __shfl_xor(acc[bb].w, off);
        }
    }
    if ((s & 7) == 0) {
        #pragma unroll
        for (int bb = 0; bb < 8; ++bb) part4[tid >> 6][bb][d4] = acc[bb];
    }
    __syncthreads();
    {
        const int bb = tid >> 5, col = tid & 31;
        float q2 = bq2[col];
        #pragma unroll
        for (int wv = 0; wv < 4; ++wv) {
            const float* pf = reinterpret_cast<const float*>(&part4[wv][bb][col >> 2]);
            q2 += pf[col & 3];
        }
        s_q2[bb][col] = q2;
    }
    __syncthreads();
    if (tid < 128) {
        const int bb = tid >> 4, r = tid & 15;
        const int b = b0 + bb;
        float sc = 0.f;
        #pragma unroll
        for (int d = 0; d < 32; ++d) sc += s_q2[bb][d] * s_k2[r * 32 + d];
        sc /= TEMP;
        float u = u_rule[(size_t)b * 16 + r];
        float g = -logf(-logf(u + EPSG) + EPSG);
        float pm = sc + g;
        int idx = r;
        #pragma unroll
        for (int off = 8; off >= 1; off >>= 1) {
            float pv = __shfl_xor(pm, off, 16);
            int   pi = __shfl_xor(idx, off, 16);
            if (pv > pm || (pv == pm && pi < idx)) { pm = pv; idx = pi; }
        }
        if (r == 0) rselbuf[b] = idx;
    }
}

// ---------- K3: wave-per-item MLP + output write (no LDS, no barriers) -----
// block = 4 b's, one per wave; comb in 16 regs (shfl broadcast); W1/W2 from
// L2 (all 16 W1s = 1 MB, L2-resident). h1 reassociation only perturbs output
// values ~1e-6 (<< threshold); selections already fixed upstream.
__launch_bounds__(256, 2)
__global__ void k3_kernel(const float* __restrict__ hidden,
                          const float* __restrict__ W1,
                          const float* __restrict__ W2,
                          const int* __restrict__ selbuf,
                          const int* __restrict__ rselbuf,
                          float* __restrict__ outbuf) {
    const int tid  = threadIdx.x;
    const int lane = tid & 63;
    const int b    = blockIdx.x * 4 + (tid >> 6);

    const int sv = selbuf[b];
    const int r  = rselbuf[b];
    const int js = sv & 7, cs = sv >> 3;

    // ---- A: comb[1024] = [h_p | h_c]; lane holds creg[j] = comb[lane*16+j]
    float creg[16];
    {
        const float* src = (lane < 32)
            ? hidden + ((size_t)b * 8 + js) * 512 + lane * 16
            : hidden + ((size_t)b * 8 + cs) * 512 + (lane - 32) * 16;
        #pragma unroll
        for (int q = 0; q < 4; ++q) {
            float4 v = *reinterpret_cast<const float4*>(src + q * 4);
            creg[q * 4 + 0] = v.x; creg[q * 4 + 1] = v.y;
            creg[q * 4 + 2] = v.z; creg[q * 4 + 3] = v.w;
        }
    }

    // ---- B: h1 partials; lane = (e4 = lane&3 -> h1 cols e4*4..+3,
    //         s = lane>>2 -> rows s*64..+63), float4 W1 loads ----
    const int e4 = lane & 3;
    const int s  = lane >> 2;
    float4 h4 = make_float4(0.f, 0.f, 0.f, 0.f);
    {
        const float* w1p = W1 + (size_t)r * 16384 + e4 * 4;
        #pragma unroll
        for (int i16 = 0; i16 < 4; ++i16) {
            const int srcl = s * 4 + i16;
            #pragma unroll
            for (int ii = 0; ii < 16; ++ii) {
                float cv = __shfl(creg[ii], srcl);
                int row = s * 64 + i16 * 16 + ii;
                float4 w4 = *reinterpret_cast<const float4*>(w1p + row * 16);
                h4.x += cv * w4.x; h4.y += cv * w4.y;
                h4.z += cv * w4.z; h4.w += cv * w4.w;
            }
        }
    }
    #pragma unroll
    for (int off = 4; off <= 32; off <<= 1) {
        h4.x += __shfl_xor(h4.x, off);
        h4.y += __shfl_xor(h4.y, off);
        h4.z += __shfl_xor(h4.z, off);
        h4.w += __shfl_xor(h4.w, off);
    }
    h4.x = fmaxf(h4.x, 0.f); h4.y = fmaxf(h4.y, 0.f);
    h4.z = fmaxf(h4.z, 0.f); h4.w = fmaxf(h4.w, 0.f);

    // ---- C: rout cols lane*8..+7 ----
    float4 o0 = make_float4(0.f, 0.f, 0.f, 0.f);
    float4 o1 = make_float4(0.f, 0.f, 0.f, 0.f);
    {
        const float* w2p = W2 + (size_t)r * 8192 + lane * 8;
        #pragma unroll
        for (int g = 0; g < 4; ++g) {
            const int srcl = (lane & ~3) | g;   // lane holding e-group g
            float hx = __shfl(h4.x, srcl);
            float hy = __shfl(h4.y, srcl);
            float hz = __shfl(h4.z, srcl);
            float hw = __shfl(h4.w, srcl);
            float4 wa, wb;
            wa = *reinterpret_cast<const float4*>(w2p + (g * 4 + 0) * 512);
            wb = *reinterpret_cast<const float4*>(w2p + (g * 4 + 0) * 512 + 4);
            o0.x += hx * wa.x; o0.y += hx * wa.y; o0.z += hx * wa.z; o0.w += hx * wa.w;
            o1.x += hx * wb.x; o1.y += hx * wb.y; o1.z += hx * wb.z; o1.w += hx * wb.w;
            wa = *reinterpret_cast<const float4*>(w2p + (g * 4 + 1) * 512);
            wb = *reinterpret_cast<const float4*>(w2p + (g * 4 + 1) * 512 + 4);
            o0.x += hy * wa.x; o0.y += hy * wa.y; o0.z += hy * wa.z; o0.w += hy * wa.w;
            o1.x += hy * wb.x; o1.y += hy * wb.y; o1.z += hy * wb.z; o1.w += hy * wb.w;
            wa = *reinterpret_cast<const float4*>(w2p + (g * 4 + 2) * 512);
            wb = *reinterpret_cast<const float4*>(w2p + (g * 4 + 2) * 512 + 4);
            o0.x += hz * wa.x; o0.y += hz * wa.y; o0.z += hz * wa.z; o0.w += hz * wa.w;
            o1.x += hz * wb.x; o1.y += hz * wb.y; o1.z += hz * wb.z; o1.w += hz * wb.w;
            wa = *reinterpret_cast<const float4*>(w2p + (g * 4 + 3) * 512);
            wb = *reinterpret_cast<const float4*>(w2p + (g * 4 + 3) * 512 + 4);
            o0.x += hw * wa.x; o0.y += hw * wa.y; o0.z += hw * wa.z; o0.w += hw * wa.w;
            o1.x += hw * wb.x; o1.y += hw * wb.y; o1.z += hw * wb.z; o1.w += hw * wb.w;
        }
    }

    // ---- D: write all 8 slots (zeros except v == js) ----
    {
        float4 z = make_float4(0.f, 0.f, 0.f, 0.f);
        float* ob = outbuf + (size_t)b * 4096 + lane * 8;
        #pragma unroll
        for (int v = 0; v < 8; ++v) {
            bool hit = (v == js);
            *reinterpret_cast<float4*>(ob + v * 512)     = hit ? o0 : z;
            *reinterpret_cast<float4*>(ob + v * 512 + 4) = hit ? o1 : z;
        }
    }
}

extern "C" void kernel_launch(void* const* d_in, const int* in_sizes, int n_in,
                              void* d_out, int out_size, void* d_ws, size_t ws_size,
                              hipStream_t stream) {
    const float* hidden   = (const float*)d_in[0];
    const float* u_var    = (const float*)d_in[1];
    const float* u_rule   = (const float*)d_in[2];
    const float* Wq       = (const float*)d_in[3];
    const float* bq       = (const float*)d_in[4];
    const float* Wk       = (const float*)d_in[5];
    const float* bk       = (const float*)d_in[6];
    const float* rule_emb = (const float*)d_in[7];
    const float* Wq2      = (const float*)d_in[8];
    const float* bq2      = (const float*)d_in[9];
    const float* Wk2      = (const float*)d_in[10];
    const float* bk2      = (const float*)d_in[11];
    const float* W1       = (const float*)d_in[12];
    const float* W2       = (const float*)d_in[13];

    char* ws = (char*)d_ws;
    float* k2f  = (float*)(ws);              // 512 f32
    int*   sel  = (int*)(ws + 4096);         // 4096 i32
    int*   rsel = (int*)(ws + 20480);        // 4096 i32
    float* outf = (float*)d_out;

    hipLaunchKernelGGL(k1_kernel, dim3(512), dim3(256), 0, stream,
                       hidden, u_var, Wq, bq, Wk, bk,
                       rule_emb, Wk2, bk2, k2f, sel, outf);
    hipLaunchKernelGGL(k2sel_kernel, dim3(512), dim3(256), 0, stream,
                       hidden, u_rule, Wq2, bq2, k2f, sel, outf, rsel);
    hipLaunchKernelGGL(k3_kernel, dim3(1024), dim3(256), 0, stream,
                       hidden, W1, W2, sel, rsel, outf);
}

// Round 14
// 91.471 us; speedup vs baseline: 1.1875x; 1.0524x over previous
//
#include <hip/hip_runtime.h>

#define TEMP 5.656854249492380195f   // sqrt(32)
#define EPSG 1e-10f

// K1 GEMM geometry: M-tile 64 (8 b x 8 v), N 64 (q|k), K chunk 64, 8 chunks.
#define XSTR 68                      // x-tile row stride (floats)
#define WSTR 64                      // w-tile row stride

// ---------- K1: canonical LDS GEMM for q/k projection + argmax + hmean -----
// (frozen: round-11 50us version)
__launch_bounds__(256, 2)
__global__ void k1_kernel(const float* __restrict__ hidden,
                          const float* __restrict__ u_var,
                          const float* __restrict__ Wq,
                          const float* __restrict__ bq,
                          const float* __restrict__ Wk,
                          const float* __restrict__ bk,
                          const float* __restrict__ rule_emb,
                          const float* __restrict__ Wk2,
                          const float* __restrict__ bk2,
                          float* __restrict__ k2f,
                          int* __restrict__ selbuf,
                          float* __restrict__ outbuf) {
    const int tid = threadIdx.x;
    const int b0  = blockIdx.x * 8;

    __shared__ float4 smem4[(64 * XSTR + 64 * WSTR) / 4];
    float* smem = reinterpret_cast<float*>(smem4);
    float* xt = smem;
    float* wt = smem + 64 * XSTR;

    // merged K0 (block 0 only): k2 = rule_emb@Wk2 + bk2
    if (blockIdx.x == 0) {
        for (int t = tid; t < 512; t += 256) {
            int r = t >> 5, d = t & 31;
            float acc = bk2[d];
            for (int h = 0; h < 64; ++h)
                acc += rule_emb[r * 64 + h] * Wk2[h * 32 + d];
            k2f[t] = acc;
        }
    }

    const int tn = tid & 15;
    const int tm = tid >> 4;

    float4 acc0 = make_float4(0.f, 0.f, 0.f, 0.f);
    float4 acc1 = make_float4(0.f, 0.f, 0.f, 0.f);
    float4 acc2 = make_float4(0.f, 0.f, 0.f, 0.f);
    float4 acc3 = make_float4(0.f, 0.f, 0.f, 0.f);

    for (int c = 0; c < 8; ++c) {
        #pragma unroll
        for (int p = 0; p < 4; ++p) {
            int f   = p * 256 + tid;
            int row = f >> 4;
            int c4  = f & 15;
            int bb  = row >> 3, v = row & 7;
            float4 val = *reinterpret_cast<const float4*>(
                hidden + (size_t)(b0 + bb) * 4096 + v * 512 + c * 64 + c4 * 4);
            *reinterpret_cast<float4*>(&xt[row * XSTR + c4 * 4]) = val;
        }
        #pragma unroll
        for (int p = 0; p < 4; ++p) {
            int f  = p * 256 + tid;
            int k  = f >> 4;
            int n4 = f & 15;
            int h  = c * 64 + k;
            const float* src = (n4 < 8) ? (Wq + h * 32 + n4 * 4)
                                        : (Wk + h * 32 + (n4 - 8) * 4);
            *reinterpret_cast<float4*>(&wt[k * WSTR + n4 * 4]) =
                *reinterpret_cast<const float4*>(src);
        }
        __syncthreads();

        #pragma unroll 4
        for (int k4 = 0; k4 < 16; ++k4) {
            float4 x0 = *reinterpret_cast<const float4*>(&xt[(tm * 4 + 0) * XSTR + k4 * 4]);
            float4 x1 = *reinterpret_cast<const float4*>(&xt[(tm * 4 + 1) * XSTR + k4 * 4]);
            float4 x2 = *reinterpret_cast<const float4*>(&xt[(tm * 4 + 2) * XSTR + k4 * 4]);
            float4 x3 = *reinterpret_cast<const float4*>(&xt[(tm * 4 + 3) * XSTR + k4 * 4]);
            float4 w0 = *reinterpret_cast<const float4*>(&wt[(k4 * 4 + 0) * WSTR + tn * 4]);
            float4 w1 = *reinterpret_cast<const float4*>(&wt[(k4 * 4 + 1) * WSTR + tn * 4]);
            float4 w2 = *reinterpret_cast<const float4*>(&wt[(k4 * 4 + 2) * WSTR + tn * 4]);
            float4 w3 = *reinterpret_cast<const float4*>(&wt[(k4 * 4 + 3) * WSTR + tn * 4]);
            acc0.x += x0.x * w0.x + x0.y * w1.x + x0.z * w2.x + x0.w * w3.x;
            acc0.y += x0.x * w0.y + x0.y * w1.y + x0.z * w2.y + x0.w * w3.y;
            acc0.z += x0.x * w0.z + x0.y * w1.z + x0.z * w2.z + x0.w * w3.z;
            acc0.w += x0.x * w0.w + x0.y * w1.w + x0.z * w2.w + x0.w * w3.w;
            acc1.x += x1.x * w0.x + x1.y * w1.x + x1.z * w2.x + x1.w * w3.x;
            acc1.y += x1.x * w0.y + x1.y * w1.y + x1.z * w2.y + x1.w * w3.y;
            acc1.z += x1.x * w0.z + x1.y * w1.z + x1.z * w2.z + x1.w * w3.z;
            acc1.w += x1.x * w0.w + x1.y * w1.w + x1.z * w2.w + x1.w * w3.w;
            acc2.x += x2.x * w0.x + x2.y * w1.x + x2.z * w2.x + x2.w * w3.x;
            acc2.y += x2.x * w0.y + x2.y * w1.y + x2.z * w2.y + x2.w * w3.y;
            acc2.z += x2.x * w0.z + x2.y * w1.z + x2.z * w2.z + x2.w * w3.z;
            acc2.w += x2.x * w0.w + x2.y * w1.w + x2.z * w2.w + x2.w * w3.w;
            acc3.x += x3.x * w0.x + x3.y * w1.x + x3.z * w2.x + x3.w * w3.x;
            acc3.y += x3.x * w0.y + x3.y * w1.y + x3.z * w2.y + x3.w * w3.y;
            acc3.z += x3.x * w0.z + x3.y * w1.z + x3.z * w2.z + x3.w * w3.z;
            acc3.w += x3.x * w0.w + x3.y * w1.w + x3.z * w2.w + x3.w * w3.w;
        }

        {
            int bb = tid >> 5, hg = tid & 31;
            float m0 = 0.f, m1 = 0.f;
            #pragma unroll
            for (int v = 0; v < 8; ++v) {
                float2 x2 = *reinterpret_cast<const float2*>(&xt[(bb * 8 + v) * XSTR + hg * 2]);
                m0 += x2.x; m1 += x2.y;
            }
            float2 o; o.x = m0 * 0.125f; o.y = m1 * 0.125f;
            *reinterpret_cast<float2*>(outbuf + (size_t)(b0 + bb) * 4096 + c * 64 + hg * 2) = o;
        }
        __syncthreads();
    }

    {
        const float* bsrc = (tn < 8) ? (bq + tn * 4) : (bk + (tn - 8) * 4);
        float4 bias4 = *reinterpret_cast<const float4*>(bsrc);
        float4 r0, r1, r2, r3;
        r0.x = acc0.x + bias4.x; r0.y = acc0.y + bias4.y; r0.z = acc0.z + bias4.z; r0.w = acc0.w + bias4.w;
        r1.x = acc1.x + bias4.x; r1.y = acc1.y + bias4.y; r1.z = acc1.z + bias4.z; r1.w = acc1.w + bias4.w;
        r2.x = acc2.x + bias4.x; r2.y = acc2.y + bias4.y; r2.z = acc2.z + bias4.z; r2.w = acc2.w + bias4.w;
        r3.x = acc3.x + bias4.x; r3.y = acc3.y + bias4.y; r3.z = acc3.z + bias4.z; r3.w = acc3.w + bias4.w;
        float* sq = smem;
        *reinterpret_cast<float4*>(&sq[(tm * 4 + 0) * XSTR + tn * 4]) = r0;
        *reinterpret_cast<float4*>(&sq[(tm * 4 + 1) * XSTR + tn * 4]) = r1;
        *reinterpret_cast<float4*>(&sq[(tm * 4 + 2) * XSTR + tn * 4]) = r2;
        *reinterpret_cast<float4*>(&sq[(tm * 4 + 3) * XSTR + tn * 4]) = r3;
    }
    __syncthreads();

    {
        const float* sq = smem;
        const int w    = tid >> 6;
        const int lane = tid & 63;
        #pragma unroll
        for (int half = 0; half < 2; ++half) {
            const int bb = w + half * 4;
            const int b  = b0 + bb;
            const int i = lane >> 3, j = lane & 7;
            float s = 0.f;
            #pragma unroll
            for (int d4 = 0; d4 < 8; ++d4) {
                float4 qv = *reinterpret_cast<const float4*>(&sq[(bb * 8 + i) * XSTR + d4 * 4]);
                float4 kv = *reinterpret_cast<const float4*>(&sq[(bb * 8 + j) * XSTR + 32 + d4 * 4]);
                s += qv.x * kv.x + qv.y * kv.y + qv.z * kv.z + qv.w * kv.w;
            }
            s /= TEMP;
            float u = u_var[(size_t)b * 64 + lane];
            float g = -logf(-logf(u + EPSG) + EPSG);
            float pm = s + g;
            int idx = lane;
            #pragma unroll
            for (int off = 32; off >= 1; off >>= 1) {
                float pv = __shfl_xor(pm, off);
                int   pi = __shfl_xor(idx, off);
                if (pv > pm || (pv == pm && pi < idx)) { pm = pv; idx = pi; }
            }
            if (lane == 0) selbuf[b] = idx;
        }
    }
}

// ---------- K2: q2 GEMM + rule gumbel argmax -> rsel[b] (frozen) -----------
__launch_bounds__(256, 4)
__global__ void k2sel_kernel(const float* __restrict__ hidden,
                             const float* __restrict__ u_rule,
                             const float* __restrict__ Wq2,
                             const float* __restrict__ bq2,
                             const float* __restrict__ k2f,
                             const int* __restrict__ selbuf,
                             const float* __restrict__ hmeanbuf,
                             int* __restrict__ rselbuf) {
    const int tid = threadIdx.x;
    const int b0 = blockIdx.x * 8;

    __shared__ float  s_k2[512];
    __shared__ float  xt[8][256];
    __shared__ float4 part4[4][8][8];
    __shared__ float  s_q2[8][32];
    __shared__ int    s_sel8[8];

    s_k2[tid]       = k2f[tid];
    s_k2[tid + 256] = k2f[tid + 256];
    if (tid < 8) s_sel8[tid] = selbuf[b0 + tid];
    __syncthreads();

    const int d4 = tid & 7, s = tid >> 3;
    float4 acc[8];
    #pragma unroll
    for (int bb = 0; bb < 8; ++bb) acc[bb] = make_float4(0.f, 0.f, 0.f, 0.f);

    for (int kt = 0; kt < 6; ++kt) {
        float4 w[8];
        #pragma unroll
        for (int j = 0; j < 8; ++j)
            w[j] = *reinterpret_cast<const float4*>(Wq2 + (size_t)(kt * 256 + s * 8 + j) * 32 + d4 * 4);
        #pragma unroll
        for (int bb = 0; bb < 8; ++bb) {
            const int b  = b0 + bb;
            const int sv = s_sel8[bb];
            const float* src;
            if (kt < 2)      src = hidden  + ((size_t)b * 8 + (sv & 7))  * 512 + kt * 256;
            else if (kt < 4) src = hidden  + ((size_t)b * 8 + (sv >> 3)) * 512 + (kt - 2) * 256;
            else             src = hmeanbuf + (size_t)b * 4096 + (kt - 4) * 256;
            xt[bb][tid] = src[tid];
        }
        __syncthreads();
        #pragma unroll
        for (int bb = 0; bb < 8; ++bb) {
            #pragma unroll
            for (int j = 0; j < 8; ++j) {
                float x = xt[bb][s * 8 + j];
                acc[bb].x += x * w[j].x;
                acc[bb].y += x * w[j].y;
                acc[bb].z += x * w[j].z;
                acc[bb].w += x * w[j].w;
            }
        }
        __syncthreads();
    }
    #pragma unroll
    for (int off = 8; off < 64; off <<= 1) {
        #pragma unroll
        for (int bb = 0; bb < 8; ++bb) {
            acc[bb].x += __shfl_xor(acc[bb].x, off);
            acc[bb].y += __shfl_xor(acc[bb].y, off);
            acc[bb].z += __shfl_xor(acc[bb].z, off);
            acc[bb].w += __shfl_xor(acc[bb].w, off);
        }
    }
    if ((s & 7) == 0) {
        #pragma unroll
        for (int bb = 0; bb < 8; ++bb) part4[tid >> 6][bb][d4] = acc[bb];
    }
    __syncthreads();
    {
        const int bb = tid >> 5, col = tid & 31;
        float q2 = bq2[col];
        #pragma unroll
        for (int wv = 0; wv < 4; ++wv) {
            const float* pf = reinterpret_cast<const float*>(&part4[wv][bb][col >> 2]);
            q2 += pf[col & 3];
        }
        s_q2[bb][col] = q2;
    }
    __syncthreads();
    if (tid < 128) {
        const int bb = tid >> 4, r = tid & 15;
        const int b = b0 + bb;
        float sc = 0.f;
        #pragma unroll
        for (int d = 0; d < 32; ++d) sc += s_q2[bb][d] * s_k2[r * 32 + d];
        sc /= TEMP;
        float u = u_rule[(size_t)b * 16 + r];
        float g = -logf(-logf(u + EPSG) + EPSG);
        float pm = sc + g;
        int idx = r;
        #pragma unroll
        for (int off = 8; off >= 1; off >>= 1) {
            float pv = __shfl_xor(pm, off, 16);
            int   pi = __shfl_xor(idx, off, 16);
            if (pv > pm || (pv == pm && pi < idx)) { pm = pv; idx = pi; }
        }
        if (r == 0) rselbuf[b] = idx;
    }
}

// ---------- K3: block-per-b MLP (W1 from L2) + coalesced streaming write ---
// comb + rout in LDS (6.5 KB), h1 via the proven part[4][16] reduce. Thread
// t writes slot v = t>>5, cols (t&31)*16..+15 -> the block's whole 16 KB out
// region is written contiguously. 4096 blocks -> 8 blocks/CU.
__launch_bounds__(256, 4)
__global__ void k3_kernel(const float* __restrict__ hidden,
                          const float* __restrict__ W1,
                          const float* __restrict__ W2,
                          const int* __restrict__ selbuf,
                          const int* __restrict__ rselbuf,
                          float* __restrict__ outbuf) {
    const int tid = threadIdx.x;
    const int b   = blockIdx.x;

    __shared__ float comb[1024];
    __shared__ float part[4][16];
    __shared__ float s_h1[16];
    __shared__ float s_rout[512];

    const int sv = selbuf[b];
    const int r  = rselbuf[b];
    const int js = sv & 7, cs = sv >> 3;

    // stage comb = [h_p | h_c]
    {
        const float4* h4 = reinterpret_cast<const float4*>(hidden);
        float4 v;
        if (tid < 128) v = h4[((size_t)b * 8 + js) * 128 + tid];
        else           v = h4[((size_t)b * 8 + cs) * 128 + (tid - 128)];
        *reinterpret_cast<float4*>(&comb[tid * 4]) = v;
    }
    __syncthreads();

    // h1 partials: thread (e = tid&15, sl = tid>>4); W1 direct from L2
    {
        const int e  = tid & 15;
        const int sl = tid >> 4;
        const float* w1p = W1 + (size_t)r * 16384;
        float a = 0.f;
        for (int i = 0; i < 64; ++i) {
            int rr = i * 16 + sl;
            a += comb[rr] * w1p[rr * 16 + e];
        }
        a += __shfl_xor(a, 16);
        a += __shfl_xor(a, 32);
        if ((sl & 3) == 0) part[sl >> 2][e] = a;
    }
    __syncthreads();
    if (tid < 16)
        s_h1[tid] = fmaxf(part[0][tid] + part[1][tid] + part[2][tid] + part[3][tid], 0.f);
    __syncthreads();

    // rout cols tid*2, tid*2+1
    {
        const float* w2 = W2 + (size_t)r * 8192;
        int o0 = tid * 2;
        float a0 = 0.f, a1 = 0.f;
        #pragma unroll
        for (int ee = 0; ee < 16; ++ee) {
            float h1e = s_h1[ee];
            float2 ww = *reinterpret_cast<const float2*>(w2 + ee * 512 + o0);
            a0 += h1e * ww.x;
            a1 += h1e * ww.y;
        }
        s_rout[o0]     = a0;
        s_rout[o0 + 1] = a1;
    }
    __syncthreads();

    // streaming write: thread t -> slot v = t>>5, 16 cols at (t&31)*16
    {
        const int v    = tid >> 5;
        const int col0 = (tid & 31) * 16;
        float4 z = make_float4(0.f, 0.f, 0.f, 0.f);
        float4 r0 = z, r1 = z, r2 = z, r3 = z;
        if (v == js) {
            r0 = *reinterpret_cast<const float4*>(&s_rout[col0]);
            r1 = *reinterpret_cast<const float4*>(&s_rout[col0 + 4]);
            r2 = *reinterpret_cast<const float4*>(&s_rout[col0 + 8]);
            r3 = *reinterpret_cast<const float4*>(&s_rout[col0 + 12]);
        }
        float* ob = outbuf + (size_t)b * 4096 + v * 512 + col0;
        *reinterpret_cast<float4*>(ob)      = r0;
        *reinterpret_cast<float4*>(ob + 4)  = r1;
        *reinterpret_cast<float4*>(ob + 8)  = r2;
        *reinterpret_cast<float4*>(ob + 12) = r3;
    }
}

extern "C" void kernel_launch(void* const* d_in, const int* in_sizes, int n_in,
                              void* d_out, int out_size, void* d_ws, size_t ws_size,
                              hipStream_t stream) {
    const float* hidden   = (const float*)d_in[0];
    const float* u_var    = (const float*)d_in[1];
    const float* u_rule   = (const float*)d_in[2];
    const float* Wq       = (const float*)d_in[3];
    const float* bq       = (const float*)d_in[4];
    const float* Wk       = (const float*)d_in[5];
    const float* bk       = (const float*)d_in[6];
    const float* rule_emb = (const float*)d_in[7];
    const float* Wq2      = (const float*)d_in[8];
    const float* bq2      = (const float*)d_in[9];
    const float* Wk2      = (const float*)d_in[10];
    const float* bk2      = (const float*)d_in[11];
    const float* W1       = (const float*)d_in[12];
    const float* W2       = (const float*)d_in[13];

    char* ws = (char*)d_ws;
    float* k2f  = (float*)(ws);              // 512 f32
    int*   sel  = (int*)(ws + 4096);         // 4096 i32
    int*   rsel = (int*)(ws + 20480);        // 4096 i32
    float* outf = (float*)d_out;

    hipLaunchKernelGGL(k1_kernel, dim3(512), dim3(256), 0, stream,
                       hidden, u_var, Wq, bq, Wk, bk,
                       rule_emb, Wk2, bk2, k2f, sel, outf);
    hipLaunchKernelGGL(k2sel_kernel, dim3(512), dim3(256), 0, stream,
                       hidden, u_rule, Wq2, bq2, k2f, sel, outf, rsel);
    hipLaunchKernelGGL(k3_kernel, dim3(4096), dim3(256), 0, stream,
                       hidden, W1, W2, sel, rsel, outf);
}